// Round 2
// baseline (2904.659 us; speedup 1.0000x reference)
//
#include <hip/hip_runtime.h>
#include <hip/hip_bf16.h>

// Problem dims (fixed)
#define BB 4
#define SS 512      // decoder len
#define EE 1024     // encoder len
#define HH 1024     // hidden
#define VV 32000    // vocab

// ---------------------------------------------------------------------------
// Embedding: x0[b*S+s, :] = tok_emb[tok[b,s], :] + pos_emb[s, :]
// ---------------------------------------------------------------------------
__global__ __launch_bounds__(256) void embed_kernel(
    const int* __restrict__ tok, const float* __restrict__ tokE,
    const float* __restrict__ posE, float* __restrict__ x0)
{
    int bs = blockIdx.x;                 // 0 .. B*S-1
    int s  = bs & (SS - 1);
    long t = (long)tok[bs];
    const float* te = tokE + t * HH;
    const float* pe = posE + (long)s * HH;
    float* xp = x0 + (long)bs * HH;
    for (int i = threadIdx.x; i < HH; i += 256)
        xp[i] = te[i] + pe[i];
}

// ---------------------------------------------------------------------------
// Tiled GEMM (NN): C[M,N] = A[M,K] @ B[K,N] (+ bias), batched via blockIdx.z.
// 64x64 tile, BK=16, 256 threads, 4x4 accum per thread. All dims multiples of
// 64 (M,N) / 16 (K) — no bounds checks.
// ---------------------------------------------------------------------------
__global__ __launch_bounds__(256) void gemm_nn_kernel(
    const float* __restrict__ A, const float* __restrict__ Bm,
    const float* __restrict__ bias, float* __restrict__ C,
    int M, int N, int K, long sA, long sB, long sC)
{
    A  += (long)blockIdx.z * sA;
    Bm += (long)blockIdx.z * sB;
    C  += (long)blockIdx.z * sC;

    __shared__ __align__(16) float As[16][68];   // [k][m], 68*4=272B rows (16B-aligned)
    __shared__ __align__(16) float Bs[16][68];   // [k][n]

    const int tid = threadIdx.x;
    const int tx = tid & 15, ty = tid >> 4;
    const int row0 = blockIdx.y * 64, col0 = blockIdx.x * 64;

    float acc[4][4] = {};

    for (int k0 = 0; k0 < K; k0 += 16) {
        // A tile: 64 rows x 16 k. thread -> (row = tid>>2, k-chunk = (tid&3)*4)
        {
            int r  = tid >> 2;
            int kk = (tid & 3) << 2;
            const float* ap = A + (long)(row0 + r) * K + (k0 + kk);
            float a0 = ap[0], a1 = ap[1], a2 = ap[2], a3 = ap[3];
            As[kk + 0][r] = a0; As[kk + 1][r] = a1;
            As[kk + 2][r] = a2; As[kk + 3][r] = a3;
        }
        // B tile: 16 k-rows x 64 cols. thread -> (k = tid>>4, col-chunk = (tid&15)*4)
        {
            int kr = tid >> 4;
            int c  = (tid & 15) << 2;
            const float* bp = Bm + (long)(k0 + kr) * N + (col0 + c);
            Bs[kr][c + 0] = bp[0]; Bs[kr][c + 1] = bp[1];
            Bs[kr][c + 2] = bp[2]; Bs[kr][c + 3] = bp[3];
        }
        __syncthreads();
#pragma unroll
        for (int k = 0; k < 16; ++k) {
            float4 av = *(const float4*)&As[k][ty << 2];
            float4 bv = *(const float4*)&Bs[k][tx << 2];
            acc[0][0] += av.x * bv.x; acc[0][1] += av.x * bv.y; acc[0][2] += av.x * bv.z; acc[0][3] += av.x * bv.w;
            acc[1][0] += av.y * bv.x; acc[1][1] += av.y * bv.y; acc[1][2] += av.y * bv.z; acc[1][3] += av.y * bv.w;
            acc[2][0] += av.z * bv.x; acc[2][1] += av.z * bv.y; acc[2][2] += av.z * bv.z; acc[2][3] += av.z * bv.w;
            acc[3][0] += av.w * bv.x; acc[3][1] += av.w * bv.y; acc[3][2] += av.w * bv.z; acc[3][3] += av.w * bv.w;
        }
        __syncthreads();
    }

    float bv4[4] = {0.f, 0.f, 0.f, 0.f};
    if (bias) {
        const float* bp = bias + col0 + (tx << 2);
        bv4[0] = bp[0]; bv4[1] = bp[1]; bv4[2] = bp[2]; bv4[3] = bp[3];
    }
#pragma unroll
    for (int i = 0; i < 4; ++i) {
        long row = row0 + (ty << 2) + i;
        float* cp = C + row * (long)N + col0 + (tx << 2);
#pragma unroll
        for (int j = 0; j < 4; ++j) cp[j] = acc[i][j] + bv4[j];
    }
}

// ---------------------------------------------------------------------------
// Tiled GEMM (NT): C[M,N] = A[M,K] @ B[N,K]^T  (scores = q @ k^T), fp32.
// ---------------------------------------------------------------------------
__global__ __launch_bounds__(256) void gemm_nt_kernel(
    const float* __restrict__ A, const float* __restrict__ Bm,
    float* __restrict__ C, int M, int N, int K, long sA, long sB, long sC)
{
    A  += (long)blockIdx.z * sA;
    Bm += (long)blockIdx.z * sB;
    C  += (long)blockIdx.z * sC;

    __shared__ __align__(16) float As[16][68];
    __shared__ __align__(16) float Bs[16][68];

    const int tid = threadIdx.x;
    const int tx = tid & 15, ty = tid >> 4;
    const int row0 = blockIdx.y * 64, col0 = blockIdx.x * 64;

    float acc[4][4] = {};

    for (int k0 = 0; k0 < K; k0 += 16) {
        {
            int r  = tid >> 2;
            int kk = (tid & 3) << 2;
            const float* ap = A + (long)(row0 + r) * K + (k0 + kk);
            As[kk + 0][r] = ap[0]; As[kk + 1][r] = ap[1];
            As[kk + 2][r] = ap[2]; As[kk + 3][r] = ap[3];
        }
        {
            int n  = tid >> 2;
            int kk = (tid & 3) << 2;
            const float* bp = Bm + (long)(col0 + n) * K + (k0 + kk);
            Bs[kk + 0][n] = bp[0]; Bs[kk + 1][n] = bp[1];
            Bs[kk + 2][n] = bp[2]; Bs[kk + 3][n] = bp[3];
        }
        __syncthreads();
#pragma unroll
        for (int k = 0; k < 16; ++k) {
            float4 av = *(const float4*)&As[k][ty << 2];
            float4 bv = *(const float4*)&Bs[k][tx << 2];
            acc[0][0] += av.x * bv.x; acc[0][1] += av.x * bv.y; acc[0][2] += av.x * bv.z; acc[0][3] += av.x * bv.w;
            acc[1][0] += av.y * bv.x; acc[1][1] += av.y * bv.y; acc[1][2] += av.y * bv.z; acc[1][3] += av.y * bv.w;
            acc[2][0] += av.z * bv.x; acc[2][1] += av.z * bv.y; acc[2][2] += av.z * bv.z; acc[2][3] += av.z * bv.w;
            acc[3][0] += av.w * bv.x; acc[3][1] += av.w * bv.y; acc[3][2] += av.w * bv.z; acc[3][3] += av.w * bv.w;
        }
        __syncthreads();
    }
#pragma unroll
    for (int i = 0; i < 4; ++i) {
        long row = row0 + (ty << 2) + i;
        float* cp = C + row * (long)N + col0 + (tx << 2);
#pragma unroll
        for (int j = 0; j < 4; ++j) cp[j] = acc[i][j];
    }
}

// ---------------------------------------------------------------------------
// Row softmax with scale + optional causal mask. One 256-thread block per row.
// Zeroes the masked tail so the PV GEMM can run over the full K dim.
// ---------------------------------------------------------------------------
__global__ __launch_bounds__(256) void softmax_kernel(
    float* __restrict__ sc, int S, int rowlen, int causal, float scale)
{
    long rid = blockIdx.x;           // b*S + i
    int i = (int)(rid % S);
    int L = causal ? (i + 1) : rowlen;
    float* row = sc + rid * (long)rowlen;
    int tid = threadIdx.x;

    __shared__ float redA[4];
    __shared__ float redB[4];

    float m = -1e30f;
    for (int j = tid; j < L; j += 256) m = fmaxf(m, row[j] * scale);
#pragma unroll
    for (int off = 32; off > 0; off >>= 1) m = fmaxf(m, __shfl_down(m, off, 64));
    if ((tid & 63) == 0) redA[tid >> 6] = m;
    __syncthreads();
    m = fmaxf(fmaxf(redA[0], redA[1]), fmaxf(redA[2], redA[3]));

    float s = 0.f;
    for (int j = tid; j < L; j += 256) {
        float e = __expf(row[j] * scale - m);
        row[j] = e;
        s += e;
    }
#pragma unroll
    for (int off = 32; off > 0; off >>= 1) s += __shfl_down(s, off, 64);
    if ((tid & 63) == 0) redB[tid >> 6] = s;
    __syncthreads();
    s = redB[0] + redB[1] + redB[2] + redB[3];
    float inv = 1.f / s;

    for (int j = tid; j < L; j += 256) row[j] *= inv;
    for (int j = L + tid; j < rowlen; j += 256) row[j] = 0.f;   // masked tail -> 0
}

// ---------------------------------------------------------------------------
extern "C" void kernel_launch(void* const* d_in, const int* in_sizes, int n_in,
                              void* d_out, int out_size, void* d_ws, size_t ws_size,
                              hipStream_t stream)
{
    const float* enc   = (const float*)d_in[0];   // [4,1024,1024]
    const int*   tok   = (const int*)  d_in[1];   // [4,512]
    const float* tokE  = (const float*)d_in[2];   // [32000,1024]
    const float* posE  = (const float*)d_in[3];   // [2048,1024]
    const float* Wq_s  = (const float*)d_in[4];
    const float* bq_s  = (const float*)d_in[5];
    const float* Wk_s  = (const float*)d_in[6];
    const float* bk_s  = (const float*)d_in[7];
    const float* Wv_s  = (const float*)d_in[8];
    const float* bv_s  = (const float*)d_in[9];
    const float* Wq_c  = (const float*)d_in[10];
    const float* bq_c  = (const float*)d_in[11];
    const float* Wk_c  = (const float*)d_in[12];
    const float* bk_c  = (const float*)d_in[13];
    const float* Wv_c  = (const float*)d_in[14];
    const float* bv_c  = (const float*)d_in[15];
    const float* Wout  = (const float*)d_in[16];  // [1024,32000]
    const float* bout  = (const float*)d_in[17];  // [32000]
    float* out = (float*)d_out;                   // [4,512,32000] fp32

    // Compact workspace layout (floats), lifetime-overlapped. 1M = 1,048,576.
    //   [ 0, 2M): x0, later x2
    //   [ 2, 4M): q (self), later qC
    //   [ 4, 6M): k (self), later x1
    //   [ 6, 8M): v (self)        }
    //   [ 8, 9M): scS             }-- kC overlays [6,10M) after step 5
    //   [ 6,10M): kC (cross K)
    //   [10,14M): vC (cross V)
    //   [14,16M): scC
    // Total 16M floats = 64 MB.
    float* ws = (float*)d_ws;
    const long M1 = 1048576;
    float* x0   = ws + 0 * M1;
    float* q    = ws + 2 * M1;
    float* kbuf = ws + 4 * M1;
    float* vbuf = ws + 6 * M1;
    float* scS  = ws + 8 * M1;
    float* kC   = ws + 6 * M1;   // overlays v,scS (dead after step 5)
    float* vC   = ws + 10 * M1;
    float* scC  = ws + 14 * M1;
    float* x1   = ws + 4 * M1;   // overlays k (dead after step 3)
    float* qC   = ws + 2 * M1;   // overlays q (dead after step 3)
    float* x2   = ws + 0 * M1;   // overlays x0 (dead after step 2)

    dim3 blk(256);
    const float scale = 0.03125f;  // 1/sqrt(1024)

    // 1) embedding
    embed_kernel<<<BB * SS, blk, 0, stream>>>(tok, tokE, posE, x0);

    // 2) self-attn projections q,k,v = x0 @ W + b   [2048,1024]
    dim3 gProj(HH / 64, (BB * SS) / 64, 1);
    gemm_nn_kernel<<<gProj, blk, 0, stream>>>(x0, Wq_s, bq_s, q,    BB*SS, HH, HH, 0, 0, 0);
    gemm_nn_kernel<<<gProj, blk, 0, stream>>>(x0, Wk_s, bk_s, kbuf, BB*SS, HH, HH, 0, 0, 0);
    gemm_nn_kernel<<<gProj, blk, 0, stream>>>(x0, Wv_s, bv_s, vbuf, BB*SS, HH, HH, 0, 0, 0);

    // 3) self scores [b,512,512] = q @ k^T
    dim3 gScS(SS / 64, SS / 64, BB);
    gemm_nt_kernel<<<gScS, blk, 0, stream>>>(q, kbuf, scS, SS, SS, HH,
                                             (long)SS * HH, (long)SS * HH, (long)SS * SS);
    // 4) causal softmax
    softmax_kernel<<<BB * SS, blk, 0, stream>>>(scS, SS, SS, 1, scale);

    // 5) x1 = P @ v   [b,512,1024], K=512
    dim3 gPV1(HH / 64, SS / 64, BB);
    gemm_nn_kernel<<<gPV1, blk, 0, stream>>>(scS, vbuf, nullptr, x1, SS, HH, SS,
                                             (long)SS * SS, (long)SS * HH, (long)SS * HH);

    // 6) cross q = x1 @ Wq_c + bq_c
    gemm_nn_kernel<<<gProj, blk, 0, stream>>>(x1, Wq_c, bq_c, qC, BB*SS, HH, HH, 0, 0, 0);

    // 7) cross k,v = enc @ W + b   (enc as [4096,1024])
    dim3 gEnc(HH / 64, (BB * EE) / 64, 1);
    gemm_nn_kernel<<<gEnc, blk, 0, stream>>>(enc, Wk_c, bk_c, kC, BB*EE, HH, HH, 0, 0, 0);
    gemm_nn_kernel<<<gEnc, blk, 0, stream>>>(enc, Wv_c, bv_c, vC, BB*EE, HH, HH, 0, 0, 0);

    // 8) cross scores [b,512,1024] = q_c @ k_c^T
    dim3 gScC(EE / 64, SS / 64, BB);
    gemm_nt_kernel<<<gScC, blk, 0, stream>>>(qC, kC, scC, SS, EE, HH,
                                             (long)SS * HH, (long)EE * HH, (long)SS * EE);
    // 9) softmax (no mask)
    softmax_kernel<<<BB * SS, blk, 0, stream>>>(scC, SS, EE, 0, scale);

    // 10) x2 = P @ v_c   [b,512,1024], K=1024
    dim3 gPV2(HH / 64, SS / 64, BB);
    gemm_nn_kernel<<<gPV2, blk, 0, stream>>>(scC, vC, nullptr, x2, SS, HH, EE,
                                             (long)SS * EE, (long)EE * HH, (long)SS * HH);

    // 11) logits = x2 @ Wout + bout  -> fp32 out [2048,32000]
    dim3 gOut(VV / 64, (BB * SS) / 64, 1);
    gemm_nn_kernel<<<gOut, blk, 0, stream>>>(x2, Wout, bout, out, BB*SS, VV, HH, 0, 0, 0);
}